// Round 9
// baseline (1536.215 us; speedup 1.0000x reference)
//
#include <hip/hip_runtime.h>
#include <hip/hip_bf16.h>
#include <stdint.h>

// Problem constants (B=4, S=4096, D=2048, F=8192)
#define BS_M 16384
#define DD   2048
#define FF   8192

typedef __attribute__((ext_vector_type(8))) short bf16x8;
typedef __attribute__((ext_vector_type(4))) float f32x4;

__device__ __forceinline__ void load_lds16(const void* g, void* l) {
  __builtin_amdgcn_global_load_lds(
      (const __attribute__((address_space(1))) uint32_t*)g,
      (__attribute__((address_space(3))) uint32_t*)l,
      16, 0, 0);
}

__device__ __forceinline__ ushort f2bf(float v) {
  __hip_bfloat16 b = __float2bfloat16(v);
  return *reinterpret_cast<ushort*>(&b);
}

#define SBAR() asm volatile("s_barrier" ::: "memory")
#define VMCNT(n)                                             \
  do {                                                       \
    asm volatile("s_waitcnt vmcnt(" #n ")" ::: "memory");    \
    __builtin_amdgcn_sched_barrier(0);                       \
  } while (0)

// ---------------- amax reduction over |x| (4x unrolled ILP) ----------------
__global__ void amax_kernel(const float4* __restrict__ x, int n4,
                            unsigned* __restrict__ amax) {
  float m = 0.f;
  const int stride = gridDim.x * blockDim.x;
  int i = blockIdx.x * blockDim.x + threadIdx.x;
  for (; i + 3 * stride < n4; i += 4 * stride) {
    float4 a = x[i];
    float4 b = x[i + stride];
    float4 c = x[i + 2 * stride];
    float4 d = x[i + 3 * stride];
    float ma = fmaxf(fmaxf(fabsf(a.x), fabsf(a.y)), fmaxf(fabsf(a.z), fabsf(a.w)));
    float mb = fmaxf(fmaxf(fabsf(b.x), fabsf(b.y)), fmaxf(fabsf(b.z), fabsf(b.w)));
    float mc = fmaxf(fmaxf(fabsf(c.x), fabsf(c.y)), fmaxf(fabsf(c.z), fabsf(c.w)));
    float md = fmaxf(fmaxf(fabsf(d.x), fabsf(d.y)), fmaxf(fabsf(d.z), fabsf(d.w)));
    m = fmaxf(m, fmaxf(fmaxf(ma, mb), fmaxf(mc, md)));
  }
  for (; i < n4; i += stride) {
    float4 a = x[i];
    m = fmaxf(m, fmaxf(fmaxf(fabsf(a.x), fabsf(a.y)),
                       fmaxf(fabsf(a.z), fabsf(a.w))));
  }
#pragma unroll
  for (int o = 32; o; o >>= 1) m = fmaxf(m, __shfl_xor(m, o));
  __shared__ float wm[4];
  if ((threadIdx.x & 63) == 0) wm[threadIdx.x >> 6] = m;
  __syncthreads();
  if (threadIdx.x == 0) {
    m = fmaxf(fmaxf(wm[0], wm[1]), fmaxf(wm[2], wm[3]));
    atomicMax(amax, __float_as_uint(m));  // magnitudes >=0: uint order == float order
  }
}

// ------------- quantize (bit-exact) + x -> bf16 (4x unrolled) -------------
__global__ void quant_cvt(const float4* __restrict__ x, ushort* __restrict__ xbf,
                          float4* __restrict__ q, float* __restrict__ scale_out,
                          const unsigned* __restrict__ amax_bits, int n4) {
  const float amax = fmaxf(__uint_as_float(*amax_bits), 1e-12f);
  const float scale = 448.0f / amax;
  if (blockIdx.x == 0 && threadIdx.x == 0) *scale_out = scale;
  const int stride = gridDim.x * blockDim.x;
  int i = blockIdx.x * blockDim.x + threadIdx.x;
  for (; i + 3 * stride < n4; i += 4 * stride) {
    float4 v[4];
    v[0] = x[i]; v[1] = x[i + stride]; v[2] = x[i + 2 * stride]; v[3] = x[i + 3 * stride];
#pragma unroll
    for (int u = 0; u < 4; ++u) {
      int idx = i + u * stride;
      ushort4 b;
      b.x = f2bf(v[u].x); b.y = f2bf(v[u].y); b.z = f2bf(v[u].z); b.w = f2bf(v[u].w);
      *(ushort4*)&xbf[(size_t)idx * 4] = b;
      float4 qq;  // int16 cast truncates toward zero -> truncf
      qq.x = truncf(fminf(fmaxf(v[u].x * scale, -448.f), 448.f));
      qq.y = truncf(fminf(fmaxf(v[u].y * scale, -448.f), 448.f));
      qq.z = truncf(fminf(fmaxf(v[u].z * scale, -448.f), 448.f));
      qq.w = truncf(fminf(fmaxf(v[u].w * scale, -448.f), 448.f));
      q[idx] = qq;
    }
  }
  for (; i < n4; i += stride) {
    float4 v = x[i];
    ushort4 b;
    b.x = f2bf(v.x); b.y = f2bf(v.y); b.z = f2bf(v.z); b.w = f2bf(v.w);
    *(ushort4*)&xbf[(size_t)i * 4] = b;
    float4 qq;
    qq.x = truncf(fminf(fmaxf(v.x * scale, -448.f), 448.f));
    qq.y = truncf(fminf(fmaxf(v.y * scale, -448.f), 448.f));
    qq.z = truncf(fminf(fmaxf(v.z * scale, -448.f), 448.f));
    qq.w = truncf(fminf(fmaxf(v.w * scale, -448.f), 448.f));
    q[i] = qq;
  }
}

// ---------------- f32 [R][C] -> bf16 transposed [C][R] ----------------
__global__ void transpose_cvt(const float* __restrict__ in,
                              ushort* __restrict__ out, int R, int C) {
  __shared__ float tile[32][33];
  const int tx = threadIdx.x, ty = threadIdx.y;
  const int c0 = blockIdx.x << 5, r0 = blockIdx.y << 5;
#pragma unroll
  for (int i = 0; i < 32; i += 8)
    tile[ty + i][tx] = in[(size_t)(r0 + ty + i) * C + c0 + tx];
  __syncthreads();
#pragma unroll
  for (int i = 0; i < 32; i += 8)
    out[(size_t)(c0 + ty + i) * R + r0 + tx] = f2bf(tile[tx][ty + i]);
}

// ================= 256x256 8-phase bf16 GEMM (T1+T2+T3+T4+T5) =================
// C[M][N] = A[M][K] * Bt[N][K]^T + bias ; FUSE=1: exact GELU + bf16 store.
// BK=64 per tile, staged as 4 units {A-k0,B-k0,A-k1,B-k1} of 16 KiB; 2-deep
// LDS dbuf (128 KiB). 8 waves = 2Mx4N, per-wave output 128x64 (acc[8][4]).
// 4 phases/tile; counted vmcnt(4) twice per tile (derived: 2 loads/unit x 2
// units allowed in flight), never 0 in main loop. LDS swizzle: byte ^=
// ((byte>>7)&3)<<4 (64B rows; 8-way -> 2-way conflict), applied as inverse-
// permuted global SOURCE (gload_lds writes linearly) + swizzled ds_read.
template <int FUSE>
__global__ __launch_bounds__(512, 1) void gemm8p(
    const ushort* __restrict__ A, const ushort* __restrict__ Bt,
    const float* __restrict__ bias, void* __restrict__ Cv,
    int M, int N, int K) {
  __shared__ ushort lds[8 * 8192];  // [c][mat][kh] units of 16 KiB = 128 KiB

  const int tiles_n = N >> 8;
  const int nwg = gridDim.x;           // % 8 == 0 for our shapes
  const int q8 = nwg >> 3;
  const int b = blockIdx.x;
  const int swz = (b & 7) * q8 + (b >> 3);  // bijective XCD chunking
  const int brow = (swz / tiles_n) << 8;
  const int bcol = (swz % tiles_n) << 8;

  const int tid = threadIdx.x;
  const int wave = tid >> 6, lane = tid & 63;
  const int wr = wave >> 2, wc = wave & 3;
  const int fr = lane & 15, kg = lane >> 4;

  // staging geometry: per round, thread covers 16B; row = tid>>2, granule = tid&3
  const int srow = tid >> 2;
  const int g2e = (((tid & 3) ^ ((tid >> 3) & 3)) << 3);  // inv-swizzled src elem off
  const size_t aoff0 = (size_t)(brow + srow) * K;
  const size_t aoff1 = (size_t)(brow + 128 + srow) * K;
  const size_t boff0 = (size_t)(bcol + srow) * K;
  const size_t boff1 = (size_t)(bcol + 128 + srow) * K;

  // ds_read addressing (ushort units). rows are 64B; swizzle key = (row>>1)&3
  const int rkey = ((fr >> 1) & 3) << 4;           // byte key
  const int gsel = (((kg << 4) ^ rkey)) >> 1;      // ushort offset in row
  const int abase = (wr * 128 + fr) * 32 + gsel;   // + m*512
  const int bbase = (wc * 64 + fr) * 32 + gsel;    // + n*512

#define U(c, mat, kh) (lds + (((c) * 4 + (mat) * 2 + (kh)) << 13))
#define STAGE_A(u, kcol)                                       \
  do {                                                         \
    load_lds16(A + aoff0 + (kcol) + g2e, (u) + wave * 512);    \
    load_lds16(A + aoff1 + (kcol) + g2e, (u) + 4096 + wave * 512); \
  } while (0)
#define STAGE_B(u, kcol)                                       \
  do {                                                         \
    load_lds16(Bt + boff0 + (kcol) + g2e, (u) + wave * 512);   \
    load_lds16(Bt + boff1 + (kcol) + g2e, (u) + 4096 + wave * 512); \
  } while (0)
#define RD_A(u)                                                \
  {                                                            \
    _Pragma("unroll") for (int m = 0; m < 8; ++m)              \
        aF[m] = *(const bf16x8*)((u) + abase + m * 512);       \
  }
#define RD_B01(u)                                              \
  {                                                            \
    bF[0] = *(const bf16x8*)((u) + bbase);                     \
    bF[1] = *(const bf16x8*)((u) + bbase + 512);               \
  }
#define RD_B23(u)                                              \
  {                                                            \
    bF[2] = *(const bf16x8*)((u) + bbase + 1024);              \
    bF[3] = *(const bf16x8*)((u) + bbase + 1536);              \
  }
#define MM(n0)                                                             \
  {                                                                        \
    __builtin_amdgcn_s_setprio(1);                                         \
    _Pragma("unroll") for (int m = 0; m < 8; ++m) {                        \
      acc[m][n0] = __builtin_amdgcn_mfma_f32_16x16x32_bf16(                \
          aF[m], bF[n0], acc[m][n0], 0, 0, 0);                             \
      acc[m][(n0) + 1] = __builtin_amdgcn_mfma_f32_16x16x32_bf16(          \
          aF[m], bF[(n0) + 1], acc[m][(n0) + 1], 0, 0, 0);                 \
    }                                                                      \
    __builtin_amdgcn_s_setprio(0);                                         \
  }

  f32x4 acc[8][4] = {};
  bf16x8 aF[8];
  bf16x8 bF[4];

  const int NT = K >> 6;

  // prologue: tile 0 -> buf 0, issue order A-k0, B-k0, A-k1, B-k1
  STAGE_A(U(0, 0, 0), 0);
  STAGE_B(U(0, 1, 0), 0);
  STAGE_A(U(0, 0, 1), 32);
  STAGE_B(U(0, 1, 1), 32);
  VMCNT(4);  // A-k0(0), B-k0(0) landed; A-k1(0), B-k1(0) may be in flight
  SBAR();

  for (int t = 0; t < NT - 1; ++t) {
    const int c = t & 1;
    const int kn = (t + 1) << 6;
    ushort* uA0 = U(c, 0, 0);
    ushort* uB0 = U(c, 1, 0);
    ushort* uA1 = U(c, 0, 1);
    ushort* uB1 = U(c, 1, 1);
    // P0: kk=0, n=0..1
    RD_A(uA0);
    RD_B01(uB0);
    STAGE_A(U(c ^ 1, 0, 0), kn);
    SBAR();
    MM(0);
    SBAR();
    // P1: kk=0, n=2..3
    RD_B23(uB0);
    STAGE_B(U(c ^ 1, 1, 0), kn);
    SBAR();
    MM(2);
    VMCNT(4);  // retire A-k1(t), B-k1(t) before P2 reads
    SBAR();
    // P2: kk=1, n=0..1
    RD_A(uA1);
    RD_B01(uB1);
    STAGE_A(U(c ^ 1, 0, 1), kn + 32);
    SBAR();
    MM(0);
    SBAR();
    // P3: kk=1, n=2..3
    RD_B23(uB1);
    STAGE_B(U(c ^ 1, 1, 1), kn + 32);
    SBAR();
    MM(2);
    VMCNT(4);  // retire A-k0(t+1), B-k0(t+1) before next P0 reads
    SBAR();
  }

  // epilogue tile NT-1 (no stages)
  {
    const int c = (NT - 1) & 1;
    RD_A(U(c, 0, 0));
    RD_B01(U(c, 1, 0));
    SBAR();
    MM(0);
    SBAR();
    RD_B23(U(c, 1, 0));
    SBAR();
    MM(2);
    VMCNT(0);  // drain A-k1, B-k1 of last tile
    SBAR();
    RD_A(U(c, 0, 1));
    RD_B01(U(c, 1, 1));
    SBAR();
    MM(0);
    SBAR();
    RD_B23(U(c, 1, 1));
    MM(2);
  }

  // C-write: C/D layout col=lane&15, row=(lane>>4)*4+r  [m89 verified]
  float bv[4];
#pragma unroll
  for (int n = 0; n < 4; ++n) bv[n] = bias[bcol + wc * 64 + n * 16 + fr];
#pragma unroll
  for (int m = 0; m < 8; ++m) {
    const int r0 = brow + wr * 128 + m * 16 + kg * 4;
#pragma unroll
    for (int n = 0; n < 4; ++n) {
      const int col = bcol + wc * 64 + n * 16 + fr;
#pragma unroll
      for (int r = 0; r < 4; ++r) {
        float v = acc[m][n][r] + bv[n];
        if (FUSE) {
          v = 0.5f * v * (1.0f + erff(v * 0.70710678118f));  // exact GELU
          ((ushort*)Cv)[(size_t)(r0 + r) * N + col] = f2bf(v);
        } else {
          ((float*)Cv)[(size_t)(r0 + r) * N + col] = v;
        }
      }
    }
  }
#undef U
#undef STAGE_A
#undef STAGE_B
#undef RD_A
#undef RD_B01
#undef RD_B23
#undef MM
}

extern "C" void kernel_launch(void* const* d_in, const int* in_sizes, int n_in,
                              void* d_out, int out_size, void* d_ws,
                              size_t ws_size, hipStream_t stream) {
  const float* x  = (const float*)d_in[0];
  const float* W1 = (const float*)d_in[1];
  const float* b1 = (const float*)d_in[2];
  const float* W2 = (const float*)d_in[3];
  const float* b2 = (const float*)d_in[4];

  const size_t MD = (size_t)BS_M * DD;  // 33,554,432
  const size_t MF = (size_t)BS_M * FF;  // 134,217,728
  const size_t DF = (size_t)DD * FF;    // 16,777,216

  // d_out: [ out f32 | q (int16 values as f32) | scale ]
  float* out_mlp = (float*)d_out;
  float* q_out   = out_mlp + MD;
  float* s_out   = out_mlp + 2 * MD;

  // ws: xbf | W1^T bf16 | W2^T bf16 | H bf16 | amax  (~384 MB)
  ushort* xbf = (ushort*)d_ws;
  ushort* w1t = xbf + MD;
  ushort* w2t = w1t + DF;
  ushort* hbf = w2t + DF;
  unsigned* amax = (unsigned*)(hbf + MF);

  hipMemsetAsync(amax, 0, sizeof(unsigned), stream);

  const int n4 = (int)(MD / 4);
  amax_kernel<<<2048, 256, 0, stream>>>((const float4*)x, n4, amax);
  quant_cvt<<<2048, 256, 0, stream>>>((const float4*)x, xbf, (float4*)q_out,
                                      s_out, amax, n4);
  // W1 [D][F] -> w1t [F][D] ; W2 [F][D] -> w2t [D][F]
  transpose_cvt<<<dim3(FF / 32, DD / 32), dim3(32, 8), 0, stream>>>(W1, w1t, DD, FF);
  transpose_cvt<<<dim3(DD / 32, FF / 32), dim3(32, 8), 0, stream>>>(W2, w2t, FF, DD);
  // H = gelu(x @ W1 + b1)  [M][F] bf16
  gemm8p<1><<<(BS_M / 256) * (FF / 256), 512, 0, stream>>>(xbf, w1t, b1, hbf,
                                                           BS_M, FF, DD);
  // out = H @ W2 + b2  [M][D] f32
  gemm8p<0><<<(BS_M / 256) * (DD / 256), 512, 0, stream>>>(hbf, w2t, b2,
                                                           out_mlp, BS_M, DD, FF);
}